// Round 16
// baseline (140.991 us; speedup 1.0000x reference)
//
#include <hip/hip_runtime.h>
#include <stdint.h>

typedef unsigned int uint;
typedef unsigned short ushort;

#define NPTS  262144
#define PLANE_T_ELEMS (65536 * 32)
#define PLANE_T_BYTES ((size_t)PLANE_T_ELEMS * 2)
#define WS_PLANES_BYTES ((size_t)3 * PLANE_T_ELEMS * 2)   // 12582912
#define WS_GRB_OFF  WS_PLANES_BYTES
#define WS_HIST_OFF (WS_GRB_OFF + 65536)                  // 12648448
#define WS_PERM_OFF (WS_HIST_OFF + 16384)                 // 12664832
#define WS_NEEDED       (WS_GRB_OFF + 65536)
#define WS_SORT_NEEDED  (WS_PERM_OFF + (size_t)NPTS * 4)  // 13713408

typedef __attribute__((ext_vector_type(8))) short bf16x8;   // 8 bf16 = 4 VGPR
typedef __attribute__((ext_vector_type(4))) float f32x4;
typedef __attribute__((ext_vector_type(2))) float f32x2;

__device__ __forceinline__ ushort f2bf(float f) {
  union { float f; uint u; } v; v.f = f;
  uint r = v.u + 0x7fffu + ((v.u >> 16) & 1u);   // RNE
  return (ushort)(r >> 16);
}
__device__ __forceinline__ float bf_lo(uint u) {
  union { uint u; float f; } v; v.u = u << 16; return v.f;
}
__device__ __forceinline__ float bf_hi(uint u) {
  union { uint u; float f; } v; v.u = u & 0xffff0000u; return v.f;
}
__device__ __forceinline__ float b2f(ushort u) {
  union { uint u; float f; } v; v.u = (uint)u << 16; return v.f;
}

// ---------- prep kernels (unchanged, verified R2-R15) ----------

__global__ __launch_bounds__(256) void transpose_planes_k(
    const float* __restrict__ pxy, const float* __restrict__ pyz,
    const float* __restrict__ pxz, ushort* __restrict__ out) {
  int plane = blockIdx.x >> 8;
  int h = blockIdx.x & 255;
  const float* src = (plane == 0) ? pxy : (plane == 1) ? pyz : pxz;
  int w = threadIdx.x;
  int p = (h << 8) + w;
  uint vals[16];
#pragma unroll
  for (int c = 0; c < 32; c += 2) {
    float f0 = src[(size_t)c * 65536 + p];
    float f1 = src[(size_t)(c + 1) * 65536 + p];
    vals[c >> 1] = (uint)f2bf(f0) | ((uint)f2bf(f1) << 16);
  }
  uint4* d4 = (uint4*)(out + (size_t)plane * PLANE_T_ELEMS + (size_t)p * 32);
#pragma unroll
  for (int i = 0; i < 4; ++i)
    d4[i] = make_uint4(vals[4 * i], vals[4 * i + 1], vals[4 * i + 2], vals[4 * i + 3]);
}

// G[x][y][z] -> fragment-ordered bf16 table (verified):
// byte off = (y*2+xh)*1024 + l*16 + j*2  ->  G[x= xh*16+(l&15)][y][z= (l>>4)*8+j]
__global__ __launch_bounds__(256) void prep_grb_k(const float* __restrict__ g,
                                                  ushort* __restrict__ grb) {
  int e = blockIdx.x * 256 + threadIdx.x;   // 0..32767
  int j = e & 7;
  int l = (e >> 3) & 63;
  int xh = (e >> 9) & 1;
  int y = e >> 10;
  int x = xh * 16 + (l & 15);
  int z = ((l >> 4) << 3) + j;
  grb[e] = f2bf(g[x * 1024 + y * 32 + z]);
}

// ---------- spatial sort: counting sort by 16^3 cell ----------
__device__ __forceinline__ int cellkey(float c0, float c1, float c2) {
  float fx = (c0 * (1.0f / 1.3f) + 1.0f) * 0.5f * 255.0f;
  float fy = (c1 * (1.0f / 1.3f) + 1.0f) * 0.5f * 255.0f;
  float fz = (c2 * (1.0f / 1.3f) + 1.0f) * 0.5f * 255.0f;
  int ix = min(max((int)fx, 0), 255);
  int iy = min(max((int)fy, 0), 255);
  int iz = min(max((int)fz, 0), 255);
  return ((ix >> 4) << 8) | ((iy >> 4) << 4) | (iz >> 4);   // 0..4095
}

__global__ __launch_bounds__(256) void zero_hist_k(int* __restrict__ hist) {
  hist[blockIdx.x * 256 + threadIdx.x] = 0;
}

__global__ __launch_bounds__(256) void hist_k(const float* __restrict__ coords,
                                              int* __restrict__ hist) {
  int p = blockIdx.x * 256 + threadIdx.x;
  atomicAdd(&hist[cellkey(coords[3 * p], coords[3 * p + 1], coords[3 * p + 2])], 1);
}

// single-block exclusive scan of 4096 ints (in place)
__global__ __launch_bounds__(256) void scan_k(int* __restrict__ hist) {
  __shared__ int sums[256];
  int t = threadIdx.x;
  int base = t * 16;
  int v[16];
  int sum = 0;
#pragma unroll
  for (int i = 0; i < 16; ++i) { v[i] = hist[base + i]; sum += v[i]; }
  sums[t] = sum;
  __syncthreads();
  if (t == 0) {
    int acc = 0;
#pragma unroll 4
    for (int i = 0; i < 256; ++i) { int x = sums[i]; sums[i] = acc; acc += x; }
  }
  __syncthreads();
  int acc = sums[t];
#pragma unroll
  for (int i = 0; i < 16; ++i) { int x = v[i]; hist[base + i] = acc; acc += x; }
}

__global__ __launch_bounds__(256) void scatter_k(const float* __restrict__ coords,
                                                 int* __restrict__ off,
                                                 int* __restrict__ perm) {
  int p = blockIdx.x * 256 + threadIdx.x;
  int pos = atomicAdd(
      &off[cellkey(coords[3 * p], coords[3 * p + 1], coords[3 * p + 2])], 1);
  perm[pos] = p;
}

// ---------- bilinear sampler (verified R2-R15, verbatim) ----------
template <bool BIG, class F>
__device__ __forceinline__ void sample_plane(const ushort* __restrict__ bt,
                                             const float* __restrict__ bf,
                                             float gw, float gh, F store) {
  float fx = (gw + 1.0f) * 0.5f * 255.0f;
  float fy = (gh + 1.0f) * 0.5f * 255.0f;
  float fx0 = floorf(fx), fy0 = floorf(fy);
  float wx1 = fx - fx0, wy1 = fy - fy0;
  float wx0 = 1.0f - wx1, wy0 = 1.0f - wy1;
  int ix0 = (int)fx0, iy0 = (int)fy0;
  int ix1 = ix0 + 1, iy1 = iy0 + 1;
  bool vx0 = (ix0 >= 0) & (ix0 < 256);
  bool vx1 = (ix1 >= 0) & (ix1 < 256);
  bool vy0 = (iy0 >= 0) & (iy0 < 256);
  bool vy1 = (iy1 >= 0) & (iy1 < 256);
  float w00 = (vx0 & vy0) ? wx0 * wy0 : 0.0f;
  float w10 = (vx1 & vy0) ? wx1 * wy0 : 0.0f;
  float w01 = (vx0 & vy1) ? wx0 * wy1 : 0.0f;
  float w11 = (vx1 & vy1) ? wx1 * wy1 : 0.0f;
  int cx0 = min(max(ix0, 0), 255), cx1 = min(max(ix1, 0), 255);
  int cy0 = min(max(iy0, 0), 255), cy1 = min(max(iy1, 0), 255);
  if (BIG) {
    uint o00 = (uint)(((cy0 << 8) + cx0) << 6);
    uint o10 = (uint)(((cy0 << 8) + cx1) << 6);
    uint o01 = (uint)(((cy1 << 8) + cx0) << 6);
    uint o11 = (uint)(((cy1 << 8) + cx1) << 6);
    const char* base = (const char*)bt;
#pragma unroll
    for (int cc = 0; cc < 32; cc += 8) {
      uint4 a = *(const uint4*)(base + o00 + cc * 2);
      uint4 b = *(const uint4*)(base + o10 + cc * 2);
      uint4 c = *(const uint4*)(base + o01 + cc * 2);
      uint4 d = *(const uint4*)(base + o11 + cc * 2);
      const uint* pa = (const uint*)&a; const uint* pb = (const uint*)&b;
      const uint* pc = (const uint*)&c; const uint* pd = (const uint*)&d;
#pragma unroll
      for (int j = 0; j < 4; ++j) {
        float v0 = w00 * bf_lo(pa[j]) + w10 * bf_lo(pb[j]) +
                   w01 * bf_lo(pc[j]) + w11 * bf_lo(pd[j]);
        float v1 = w00 * bf_hi(pa[j]) + w10 * bf_hi(pb[j]) +
                   w01 * bf_hi(pc[j]) + w11 * bf_hi(pd[j]);
        store(cc + 2 * j, v0);
        store(cc + 2 * j + 1, v1);
      }
    }
  } else {
    int o00 = (cy0 << 8) + cx0, o10 = (cy0 << 8) + cx1;
    int o01 = (cy1 << 8) + cx0, o11 = (cy1 << 8) + cx1;
#pragma unroll
    for (int c = 0; c < 32; ++c) {
      const float* base = bf + (size_t)c * 65536;
      float v = w00 * base[o00] + w10 * base[o10] + w01 * base[o01] + w11 * base[o11];
      store(c, v);
    }
  }
}

// ---------- MFMA main kernel: R14 verbatim + optional point permutation ----------
__global__ __launch_bounds__(256, 4) void tucker_mfma_k(
    const float* __restrict__ coords,
    const ushort* __restrict__ planes_t,
    const ushort* __restrict__ grb,
    const int* __restrict__ perm,
    float* __restrict__ out) {
  __shared__ ushort xy_s[128][36];   // 72B rows (R4/R7-proven)
  __shared__ ushort xz_s[128][40];   // 80B rows, 16B-aligned b128 slots
  __shared__ ushort yz_s[128][36];   // 72B rows
  __shared__ float part_s[4][128];   // per-wave y-partials

  int tid = threadIdx.x;
  int l = tid & 63;
  int wv = tid >> 6;       // wave owns y = wv*8 .. wv*8+7
  int s = l & 15;
  int kb = l >> 4;

  // ---- sampling: R14 code paths, split by half (wave-uniform) ----
  int q = tid & 127;                 // point row in LDS
  int idx = blockIdx.x * 128 + q;
  int p = perm ? perm[idx] : idx;    // spatially-sorted point id
  float c0c = coords[3 * p + 0] * (1.0f / 1.3f);
  float c1c = coords[3 * p + 1] * (1.0f / 1.3f);
  float c2c = coords[3 * p + 2] * (1.0f / 1.3f);

  if (tid < 128) {
    uint buf[16];
    auto pack = [&](int c, float v) {
      ushort h = f2bf(v);
      if (c & 1) buf[c >> 1] |= ((uint)h << 16);
      else buf[c >> 1] = (uint)h;
    };
    // xy: W<-x(c0), H<-y(c1)
    sample_plane<true>(planes_t, nullptr, c0c, c1c, pack);
    uint2* r2 = (uint2*)xy_s[q];
#pragma unroll
    for (int i = 0; i < 8; ++i) r2[i] = make_uint2(buf[2 * i], buf[2 * i + 1]);
    // yz: W<-y(c1), H<-z(c2)
    sample_plane<true>(planes_t + (size_t)PLANE_T_ELEMS, nullptr, c1c, c2c, pack);
    r2 = (uint2*)yz_s[q];
#pragma unroll
    for (int i = 0; i < 8; ++i) r2[i] = make_uint2(buf[2 * i], buf[2 * i + 1]);
  } else {
    uint buf[16];
    auto pack = [&](int c, float v) {
      ushort h = f2bf(v);
      if (c & 1) buf[c >> 1] |= ((uint)h << 16);
      else buf[c >> 1] = (uint)h;
    };
    // xz: W<-x(c0), H<-z(c2)
    sample_plane<true>(planes_t + (size_t)2 * PLANE_T_ELEMS, nullptr, c0c, c2c, pack);
    uint4* r4 = (uint4*)xz_s[q];
#pragma unroll
    for (int i = 0; i < 4; ++i)
      r4[i] = make_uint4(buf[4 * i], buf[4 * i + 1], buf[4 * i + 2], buf[4 * i + 3]);
  }

  // ---- wave's 16 G-fragments (asm keep-alive; compiler may still reload) ----
  const char* gb = (const char*)grb;
  uint lbase = (uint)l * 16;
  bf16x8 greg[8][2];
#pragma unroll
  for (int yl = 0; yl < 8; ++yl) {
#pragma unroll
    for (int h = 0; h < 2; ++h)
      greg[yl][h] =
          *(const bf16x8*)(gb + (uint)((wv * 8 + yl) * 2048 + h * 1024) + lbase);
  }
#pragma unroll
  for (int yl = 0; yl < 8; ++yl) {
    asm volatile("" : "+v"(greg[yl][0]));
    asm volatile("" : "+v"(greg[yl][1]));
  }
  __syncthreads();

  // ---- main loop: d = mfma(G, xz); acc += yz[y]*d  (R14-verified scheme) ----
  f32x4 zero = {0.f, 0.f, 0.f, 0.f};
#pragma unroll 2
  for (int t = 0; t < 8; ++t) {
    int pt = t * 16 + s;
    union BF { uint4 u; bf16x8 v; } bfrag;       // B = raw xz bf16 (zero prep)
    bfrag.u = *(const uint4*)(&xz_s[pt][0] + kb * 8);
    const ushort* yr = yz_s[pt];
    uint yp[4];
    yp[0] = *(const uint*)(yr + wv * 8 + 0);
    yp[1] = *(const uint*)(yr + wv * 8 + 2);
    yp[2] = *(const uint*)(yr + wv * 8 + 4);
    yp[3] = *(const uint*)(yr + wv * 8 + 6);

    f32x2 acc0 = {0.f, 0.f}, acc1 = {0.f, 0.f};
    f32x2 acc2 = {0.f, 0.f}, acc3 = {0.f, 0.f};
#pragma unroll
    for (int qq = 0; qq < 4; ++qq) {
#pragma unroll
      for (int par = 0; par < 2; ++par) {
        float yv = par ? bf_hi(yp[qq]) : bf_lo(yp[qq]);
        union D { f32x4 v; f32x2 h[2]; } d0, d1;
        d0.v = __builtin_amdgcn_mfma_f32_16x16x32_bf16(greg[2 * qq + par][0],
                                                       bfrag.v, zero, 0, 0, 0);
        d1.v = __builtin_amdgcn_mfma_f32_16x16x32_bf16(greg[2 * qq + par][1],
                                                       bfrag.v, zero, 0, 0, 0);
        f32x2 yvv = {yv, yv};
        acc0 += d0.h[0] * yvv;
        acc1 += d0.h[1] * yvv;
        acc2 += d1.h[0] * yvv;
        acc3 += d1.h[1] * yvv;
      }
    }

    // epilogue (R14-verified D-layout: row=x=kb*4+r, col=point=s)
    const uint* xyr = (const uint*)xy_s[pt];
    uint q0 = xyr[kb * 2], q1 = xyr[kb * 2 + 1];
    uint q2 = xyr[8 + kb * 2], q3 = xyr[8 + kb * 2 + 1];
    float v = acc0[0] * bf_lo(q0) + acc0[1] * bf_hi(q0)
            + acc1[0] * bf_lo(q1) + acc1[1] * bf_hi(q1)
            + acc2[0] * bf_lo(q2) + acc2[1] * bf_hi(q2)
            + acc3[0] * bf_lo(q3) + acc3[1] * bf_hi(q3);
    v += __shfl_xor(v, 16, 64);
    v += __shfl_xor(v, 32, 64);
    if (l < 16) part_s[wv][pt] = v;   // kb==0 lanes hold pt = t*16+s
  }
  __syncthreads();

  // cross-wave sum of y-partials; write back through the permutation
  if (tid < 128) {
    int oidx = blockIdx.x * 128 + tid;
    int po = perm ? perm[oidx] : oidx;
    out[po] = part_s[0][tid] + part_s[1][tid] + part_s[2][tid] + part_s[3][tid];
  }
}

// ---------- fallback (no workspace): slow-but-correct ----------
__global__ __launch_bounds__(256) void tucker_small_k(
    const float* __restrict__ coords,
    const float* __restrict__ pxy, const float* __restrict__ pyz,
    const float* __restrict__ pxz, const float* __restrict__ g,
    float* __restrict__ out) {
  __shared__ float s_yz[256 * 33];
  int tid = threadIdx.x;
  int p = blockIdx.x * 256 + tid;
  float c0 = coords[3 * p + 0] / 1.3f;
  float c1 = coords[3 * p + 1] / 1.3f;
  float c2 = coords[3 * p + 2] / 1.3f;
  float xy[32], xz[32];
  float* yzrow = &s_yz[tid * 33];
  sample_plane<false>(nullptr, pxy, c0, c1, [&](int c, float v) { xy[c] = v; });
  sample_plane<false>(nullptr, pyz, c1, c2, [&](int c, float v) { yzrow[c] = v; });
  sample_plane<false>(nullptr, pxz, c0, c2, [&](int c, float v) { xz[c] = v; });
  float acc = 0.0f;
  for (int y = 0; y < 32; ++y) {
    float yzv = yzrow[y];
    float accy = 0.0f;
#pragma unroll
    for (int z = 0; z < 32; ++z) {
      float t0 = 0.f, t1 = 0.f, t2 = 0.f, t3 = 0.f;
#pragma unroll
      for (int x = 0; x < 32; x += 4) {
        t0 = fmaf(g[(x + 0) * 1024 + y * 32 + z], xy[x + 0], t0);
        t1 = fmaf(g[(x + 1) * 1024 + y * 32 + z], xy[x + 1], t1);
        t2 = fmaf(g[(x + 2) * 1024 + y * 32 + z], xy[x + 2], t2);
        t3 = fmaf(g[(x + 3) * 1024 + y * 32 + z], xy[x + 3], t3);
      }
      accy = fmaf((t0 + t1) + (t2 + t3), xz[z], accy);
    }
    acc = fmaf(accy, yzv, acc);
  }
  out[p] = acc;
}

extern "C" void kernel_launch(void* const* d_in, const int* in_sizes, int n_in,
                              void* d_out, int out_size, void* d_ws, size_t ws_size,
                              hipStream_t stream) {
  const float* coords = (const float*)d_in[0];
  const float* pxy = (const float*)d_in[1];
  const float* pyz = (const float*)d_in[2];
  const float* pxz = (const float*)d_in[3];
  const float* g   = (const float*)d_in[4];
  float* out = (float*)d_out;

  if (ws_size >= WS_NEEDED) {
    ushort* planes_t = (ushort*)d_ws;
    ushort* grb = (ushort*)((char*)d_ws + WS_GRB_OFF);
    hipLaunchKernelGGL(transpose_planes_k, dim3(768), dim3(256), 0, stream,
                       pxy, pyz, pxz, planes_t);
    hipLaunchKernelGGL(prep_grb_k, dim3(128), dim3(256), 0, stream, g, grb);
    int* perm = nullptr;
    if (ws_size >= WS_SORT_NEEDED) {
      int* hist = (int*)((char*)d_ws + WS_HIST_OFF);
      perm = (int*)((char*)d_ws + WS_PERM_OFF);
      hipLaunchKernelGGL(zero_hist_k, dim3(16), dim3(256), 0, stream, hist);
      hipLaunchKernelGGL(hist_k, dim3(NPTS / 256), dim3(256), 0, stream, coords,
                         hist);
      hipLaunchKernelGGL(scan_k, dim3(1), dim3(256), 0, stream, hist);
      hipLaunchKernelGGL(scatter_k, dim3(NPTS / 256), dim3(256), 0, stream, coords,
                         hist, perm);
    }
    hipLaunchKernelGGL(tucker_mfma_k, dim3(NPTS / 128), dim3(256), 0, stream,
                       coords, planes_t, grb, perm, out);
  } else {
    hipLaunchKernelGGL(tucker_small_k, dim3(NPTS / 256), dim3(256), 0, stream,
                       coords, pxy, pyz, pxz, g, out);
  }
}

// Round 17
// 60.330 us; speedup vs baseline: 2.3370x; 2.3370x over previous
//
#include <hip/hip_runtime.h>
#include <stdint.h>

typedef unsigned int uint;
typedef unsigned short ushort;

#define NPTS  262144
#define PLANE_T_ELEMS (65536 * 32)
#define PLANE_T_BYTES ((size_t)PLANE_T_ELEMS * 2)
#define WS_PLANES_BYTES ((size_t)3 * PLANE_T_ELEMS * 2)   // 12582912
#define WS_GRB_OFF  WS_PLANES_BYTES
#define WS_NEEDED   (WS_PLANES_BYTES + (size_t)32768 * 2)

typedef __attribute__((ext_vector_type(8))) short bf16x8;   // 8 bf16 = 4 VGPR
typedef __attribute__((ext_vector_type(4))) float f32x4;
typedef __attribute__((ext_vector_type(2))) float f32x2;

__device__ __forceinline__ ushort f2bf(float f) {
  union { float f; uint u; } v; v.f = f;
  uint r = v.u + 0x7fffu + ((v.u >> 16) & 1u);   // RNE
  return (ushort)(r >> 16);
}
__device__ __forceinline__ float bf_lo(uint u) {
  union { uint u; float f; } v; v.u = u << 16; return v.f;
}
__device__ __forceinline__ float bf_hi(uint u) {
  union { uint u; float f; } v; v.u = u & 0xffff0000u; return v.f;
}
__device__ __forceinline__ float b2f(ushort u) {
  union { uint u; float f; } v; v.u = (uint)u << 16; return v.f;
}

// ---------- prep kernels (unchanged, verified R2-R16) ----------

__global__ __launch_bounds__(256) void transpose_planes_k(
    const float* __restrict__ pxy, const float* __restrict__ pyz,
    const float* __restrict__ pxz, ushort* __restrict__ out) {
  int plane = blockIdx.x >> 8;
  int h = blockIdx.x & 255;
  const float* src = (plane == 0) ? pxy : (plane == 1) ? pyz : pxz;
  int w = threadIdx.x;
  int p = (h << 8) + w;
  uint vals[16];
#pragma unroll
  for (int c = 0; c < 32; c += 2) {
    float f0 = src[(size_t)c * 65536 + p];
    float f1 = src[(size_t)(c + 1) * 65536 + p];
    vals[c >> 1] = (uint)f2bf(f0) | ((uint)f2bf(f1) << 16);
  }
  uint4* d4 = (uint4*)(out + (size_t)plane * PLANE_T_ELEMS + (size_t)p * 32);
#pragma unroll
  for (int i = 0; i < 4; ++i)
    d4[i] = make_uint4(vals[4 * i], vals[4 * i + 1], vals[4 * i + 2], vals[4 * i + 3]);
}

// G[x][y][z] -> fragment-ordered bf16 table (verified):
// byte off = (y*2+xh)*1024 + l*16 + j*2  ->  G[x= xh*16+(l&15)][y][z= (l>>4)*8+j]
__global__ __launch_bounds__(256) void prep_grb_k(const float* __restrict__ g,
                                                  ushort* __restrict__ grb) {
  int e = blockIdx.x * 256 + threadIdx.x;   // 0..32767
  int j = e & 7;
  int l = (e >> 3) & 63;
  int xh = (e >> 9) & 1;
  int y = e >> 10;
  int x = xh * 16 + (l & 15);
  int z = ((l >> 4) << 3) + j;
  grb[e] = f2bf(g[x * 1024 + y * 32 + z]);
}

// ---------- bilinear sampler, BATCHED issue: all 16 tap loads, then combines.
// Identical per-channel arithmetic and order as the R2-verified sampler -> bit-exact.
template <class F>
__device__ __forceinline__ void sample_plane_b(const ushort* __restrict__ bt,
                                               float gw, float gh, F store) {
  float fx = (gw + 1.0f) * 0.5f * 255.0f;
  float fy = (gh + 1.0f) * 0.5f * 255.0f;
  float fx0 = floorf(fx), fy0 = floorf(fy);
  float wx1 = fx - fx0, wy1 = fy - fy0;
  float wx0 = 1.0f - wx1, wy0 = 1.0f - wy1;
  int ix0 = (int)fx0, iy0 = (int)fy0;
  int ix1 = ix0 + 1, iy1 = iy0 + 1;
  bool vx0 = (ix0 >= 0) & (ix0 < 256);
  bool vx1 = (ix1 >= 0) & (ix1 < 256);
  bool vy0 = (iy0 >= 0) & (iy0 < 256);
  bool vy1 = (iy1 >= 0) & (iy1 < 256);
  float w00 = (vx0 & vy0) ? wx0 * wy0 : 0.0f;
  float w10 = (vx1 & vy0) ? wx1 * wy0 : 0.0f;
  float w01 = (vx0 & vy1) ? wx0 * wy1 : 0.0f;
  float w11 = (vx1 & vy1) ? wx1 * wy1 : 0.0f;
  int cx0 = min(max(ix0, 0), 255), cx1 = min(max(ix1, 0), 255);
  int cy0 = min(max(iy0, 0), 255), cy1 = min(max(iy1, 0), 255);
  uint o00 = (uint)(((cy0 << 8) + cx0) << 6);
  uint o10 = (uint)(((cy0 << 8) + cx1) << 6);
  uint o01 = (uint)(((cy1 << 8) + cx0) << 6);
  uint o11 = (uint)(((cy1 << 8) + cx1) << 6);
  const char* base = (const char*)bt;

  uint4 T[16];                       // all taps in flight: one latency round
#pragma unroll
  for (int i = 0; i < 4; ++i) {
    T[4 * i + 0] = *(const uint4*)(base + o00 + i * 16);
    T[4 * i + 1] = *(const uint4*)(base + o10 + i * 16);
    T[4 * i + 2] = *(const uint4*)(base + o01 + i * 16);
    T[4 * i + 3] = *(const uint4*)(base + o11 + i * 16);
  }
#pragma unroll
  for (int i = 0; i < 4; ++i) {
    int cc = i * 8;
    uint4 a = T[4 * i + 0], b = T[4 * i + 1];
    uint4 c = T[4 * i + 2], d = T[4 * i + 3];
    const uint* pa = (const uint*)&a; const uint* pb = (const uint*)&b;
    const uint* pc = (const uint*)&c; const uint* pd = (const uint*)&d;
#pragma unroll
    for (int j = 0; j < 4; ++j) {
      float v0 = w00 * bf_lo(pa[j]) + w10 * bf_lo(pb[j]) +
                 w01 * bf_lo(pc[j]) + w11 * bf_lo(pd[j]);
      float v1 = w00 * bf_hi(pa[j]) + w10 * bf_hi(pb[j]) +
                 w01 * bf_hi(pc[j]) + w11 * bf_hi(pd[j]);
      store(cc + 2 * j, v0);
      store(cc + 2 * j + 1, v1);
    }
  }
}

// fp32 scalar sampler (verified R1; fallback only)
template <class F>
__device__ __forceinline__ void sample_plane_f32(const float* __restrict__ bf,
                                                 float gw, float gh, F store) {
  float fx = (gw + 1.0f) * 0.5f * 255.0f;
  float fy = (gh + 1.0f) * 0.5f * 255.0f;
  float fx0 = floorf(fx), fy0 = floorf(fy);
  float wx1 = fx - fx0, wy1 = fy - fy0;
  float wx0 = 1.0f - wx1, wy0 = 1.0f - wy1;
  int ix0 = (int)fx0, iy0 = (int)fy0;
  int ix1 = ix0 + 1, iy1 = iy0 + 1;
  bool vx0 = (ix0 >= 0) & (ix0 < 256);
  bool vx1 = (ix1 >= 0) & (ix1 < 256);
  bool vy0 = (iy0 >= 0) & (iy0 < 256);
  bool vy1 = (iy1 >= 0) & (iy1 < 256);
  float w00 = (vx0 & vy0) ? wx0 * wy0 : 0.0f;
  float w10 = (vx1 & vy0) ? wx1 * wy0 : 0.0f;
  float w01 = (vx0 & vy1) ? wx0 * wy1 : 0.0f;
  float w11 = (vx1 & vy1) ? wx1 * wy1 : 0.0f;
  int cx0 = min(max(ix0, 0), 255), cx1 = min(max(ix1, 0), 255);
  int cy0 = min(max(iy0, 0), 255), cy1 = min(max(iy1, 0), 255);
  int o00 = (cy0 << 8) + cx0, o10 = (cy0 << 8) + cx1;
  int o01 = (cy1 << 8) + cx0, o11 = (cy1 << 8) + cx1;
#pragma unroll
  for (int c = 0; c < 32; ++c) {
    const float* base = bf + (size_t)c * 65536;
    float v = w00 * base[o00] + w10 * base[o10] + w01 * base[o01] + w11 * base[o11];
    store(c, v);
  }
}

// ---------- MFMA main kernel: R14 verbatim, batched-gather sampler ----------
__global__ __launch_bounds__(256, 4) void tucker_mfma_k(
    const float* __restrict__ coords,
    const ushort* __restrict__ planes_t,
    const ushort* __restrict__ grb,
    float* __restrict__ out) {
  __shared__ ushort xy_s[128][36];   // 72B rows (R4/R7-proven)
  __shared__ ushort xz_s[128][40];   // 80B rows, 16B-aligned b128 slots
  __shared__ ushort yz_s[128][36];   // 72B rows
  __shared__ float part_s[4][128];   // per-wave y-partials

  int tid = threadIdx.x;
  int l = tid & 63;
  int wv = tid >> 6;       // wave owns y = wv*8 .. wv*8+7
  int s = l & 15;
  int kb = l >> 4;

  // ---- sampling: R14 split-by-half, batched tap issue ----
  int q = tid & 127;                 // point row in LDS
  int p = blockIdx.x * 128 + q;
  float c0c = coords[3 * p + 0] * (1.0f / 1.3f);
  float c1c = coords[3 * p + 1] * (1.0f / 1.3f);
  float c2c = coords[3 * p + 2] * (1.0f / 1.3f);

  if (tid < 128) {
    uint buf[16];
    auto pack = [&](int c, float v) {
      ushort h = f2bf(v);
      if (c & 1) buf[c >> 1] |= ((uint)h << 16);
      else buf[c >> 1] = (uint)h;
    };
    // xy: W<-x(c0), H<-y(c1)
    sample_plane_b(planes_t, c0c, c1c, pack);
    uint2* r2 = (uint2*)xy_s[q];
#pragma unroll
    for (int i = 0; i < 8; ++i) r2[i] = make_uint2(buf[2 * i], buf[2 * i + 1]);
    // yz: W<-y(c1), H<-z(c2)
    sample_plane_b(planes_t + (size_t)PLANE_T_ELEMS, c1c, c2c, pack);
    r2 = (uint2*)yz_s[q];
#pragma unroll
    for (int i = 0; i < 8; ++i) r2[i] = make_uint2(buf[2 * i], buf[2 * i + 1]);
  } else {
    uint buf[16];
    auto pack = [&](int c, float v) {
      ushort h = f2bf(v);
      if (c & 1) buf[c >> 1] |= ((uint)h << 16);
      else buf[c >> 1] = (uint)h;
    };
    // xz: W<-x(c0), H<-z(c2)
    sample_plane_b(planes_t + (size_t)2 * PLANE_T_ELEMS, c0c, c2c, pack);
    uint4* r4 = (uint4*)xz_s[q];
#pragma unroll
    for (int i = 0; i < 4; ++i)
      r4[i] = make_uint4(buf[4 * i], buf[4 * i + 1], buf[4 * i + 2], buf[4 * i + 3]);
  }

  // ---- wave's 16 G-fragments (asm keep-alive; compiler may still reload) ----
  const char* gb = (const char*)grb;
  uint lbase = (uint)l * 16;
  bf16x8 greg[8][2];
#pragma unroll
  for (int yl = 0; yl < 8; ++yl) {
#pragma unroll
    for (int h = 0; h < 2; ++h)
      greg[yl][h] =
          *(const bf16x8*)(gb + (uint)((wv * 8 + yl) * 2048 + h * 1024) + lbase);
  }
#pragma unroll
  for (int yl = 0; yl < 8; ++yl) {
    asm volatile("" : "+v"(greg[yl][0]));
    asm volatile("" : "+v"(greg[yl][1]));
  }
  __syncthreads();

  // ---- main loop: d = mfma(G, xz); acc += yz[y]*d  (R14-verified scheme) ----
  f32x4 zero = {0.f, 0.f, 0.f, 0.f};
#pragma unroll 2
  for (int t = 0; t < 8; ++t) {
    int pt = t * 16 + s;
    union BF { uint4 u; bf16x8 v; } bfrag;       // B = raw xz bf16 (zero prep)
    bfrag.u = *(const uint4*)(&xz_s[pt][0] + kb * 8);
    const ushort* yr = yz_s[pt];
    uint yp[4];
    yp[0] = *(const uint*)(yr + wv * 8 + 0);
    yp[1] = *(const uint*)(yr + wv * 8 + 2);
    yp[2] = *(const uint*)(yr + wv * 8 + 4);
    yp[3] = *(const uint*)(yr + wv * 8 + 6);

    f32x2 acc0 = {0.f, 0.f}, acc1 = {0.f, 0.f};
    f32x2 acc2 = {0.f, 0.f}, acc3 = {0.f, 0.f};
#pragma unroll
    for (int qq = 0; qq < 4; ++qq) {
#pragma unroll
      for (int par = 0; par < 2; ++par) {
        float yv = par ? bf_hi(yp[qq]) : bf_lo(yp[qq]);
        union D { f32x4 v; f32x2 h[2]; } d0, d1;
        d0.v = __builtin_amdgcn_mfma_f32_16x16x32_bf16(greg[2 * qq + par][0],
                                                       bfrag.v, zero, 0, 0, 0);
        d1.v = __builtin_amdgcn_mfma_f32_16x16x32_bf16(greg[2 * qq + par][1],
                                                       bfrag.v, zero, 0, 0, 0);
        f32x2 yvv = {yv, yv};
        acc0 += d0.h[0] * yvv;
        acc1 += d0.h[1] * yvv;
        acc2 += d1.h[0] * yvv;
        acc3 += d1.h[1] * yvv;
      }
    }

    // epilogue (R14-verified D-layout: row=x=kb*4+r, col=point=s)
    const uint* xyr = (const uint*)xy_s[pt];
    uint q0 = xyr[kb * 2], q1 = xyr[kb * 2 + 1];
    uint q2 = xyr[8 + kb * 2], q3 = xyr[8 + kb * 2 + 1];
    float v = acc0[0] * bf_lo(q0) + acc0[1] * bf_hi(q0)
            + acc1[0] * bf_lo(q1) + acc1[1] * bf_hi(q1)
            + acc2[0] * bf_lo(q2) + acc2[1] * bf_hi(q2)
            + acc3[0] * bf_lo(q3) + acc3[1] * bf_hi(q3);
    v += __shfl_xor(v, 16, 64);
    v += __shfl_xor(v, 32, 64);
    if (l < 16) part_s[wv][pt] = v;   // kb==0 lanes hold pt = t*16+s
  }
  __syncthreads();

  // cross-wave sum of y-partials (linear, exact partition of y=0..31)
  if (tid < 128)
    out[blockIdx.x * 128 + tid] =
        part_s[0][tid] + part_s[1][tid] + part_s[2][tid] + part_s[3][tid];
}

// ---------- fallback (no workspace): slow-but-correct ----------
__global__ __launch_bounds__(256) void tucker_small_k(
    const float* __restrict__ coords,
    const float* __restrict__ pxy, const float* __restrict__ pyz,
    const float* __restrict__ pxz, const float* __restrict__ g,
    float* __restrict__ out) {
  __shared__ float s_yz[256 * 33];
  int tid = threadIdx.x;
  int p = blockIdx.x * 256 + tid;
  float c0 = coords[3 * p + 0] / 1.3f;
  float c1 = coords[3 * p + 1] / 1.3f;
  float c2 = coords[3 * p + 2] / 1.3f;
  float xy[32], xz[32];
  float* yzrow = &s_yz[tid * 33];
  sample_plane_f32(pxy, c0, c1, [&](int c, float v) { xy[c] = v; });
  sample_plane_f32(pyz, c1, c2, [&](int c, float v) { yzrow[c] = v; });
  sample_plane_f32(pxz, c0, c2, [&](int c, float v) { xz[c] = v; });
  float acc = 0.0f;
  for (int y = 0; y < 32; ++y) {
    float yzv = yzrow[y];
    float accy = 0.0f;
#pragma unroll
    for (int z = 0; z < 32; ++z) {
      float t0 = 0.f, t1 = 0.f, t2 = 0.f, t3 = 0.f;
#pragma unroll
      for (int x = 0; x < 32; x += 4) {
        t0 = fmaf(g[(x + 0) * 1024 + y * 32 + z], xy[x + 0], t0);
        t1 = fmaf(g[(x + 1) * 1024 + y * 32 + z], xy[x + 1], t1);
        t2 = fmaf(g[(x + 2) * 1024 + y * 32 + z], xy[x + 2], t2);
        t3 = fmaf(g[(x + 3) * 1024 + y * 32 + z], xy[x + 3], t3);
      }
      accy = fmaf((t0 + t1) + (t2 + t3), xz[z], accy);
    }
    acc = fmaf(accy, yzv, acc);
  }
  out[p] = acc;
}

extern "C" void kernel_launch(void* const* d_in, const int* in_sizes, int n_in,
                              void* d_out, int out_size, void* d_ws, size_t ws_size,
                              hipStream_t stream) {
  const float* coords = (const float*)d_in[0];
  const float* pxy = (const float*)d_in[1];
  const float* pyz = (const float*)d_in[2];
  const float* pxz = (const float*)d_in[3];
  const float* g   = (const float*)d_in[4];
  float* out = (float*)d_out;

  if (ws_size >= WS_NEEDED) {
    ushort* planes_t = (ushort*)d_ws;
    ushort* grb = (ushort*)((char*)d_ws + WS_GRB_OFF);
    hipLaunchKernelGGL(transpose_planes_k, dim3(768), dim3(256), 0, stream,
                       pxy, pyz, pxz, planes_t);
    hipLaunchKernelGGL(prep_grb_k, dim3(128), dim3(256), 0, stream, g, grb);
    hipLaunchKernelGGL(tucker_mfma_k, dim3(NPTS / 128), dim3(256), 0, stream,
                       coords, planes_t, grb, out);
  } else {
    hipLaunchKernelGGL(tucker_small_k, dim3(NPTS / 256), dim3(256), 0, stream,
                       coords, pxy, pyz, pxz, g, out);
  }
}

// Round 18
// 58.139 us; speedup vs baseline: 2.4251x; 1.0377x over previous
//
#include <hip/hip_runtime.h>
#include <stdint.h>

typedef unsigned int uint;
typedef unsigned short ushort;

#define NPTS  262144
#define PLANE_T_ELEMS (65536 * 32)
#define PLANE_T_BYTES ((size_t)PLANE_T_ELEMS * 2)
#define WS_PLANES_BYTES ((size_t)3 * PLANE_T_ELEMS * 2)   // 12582912
#define WS_GRB_OFF  WS_PLANES_BYTES
#define WS_NEEDED   (WS_PLANES_BYTES + (size_t)32768 * 2)

typedef __attribute__((ext_vector_type(8))) short bf16x8;   // 8 bf16 = 4 VGPR
typedef __attribute__((ext_vector_type(4))) float f32x4;
typedef __attribute__((ext_vector_type(2))) float f32x2;

__device__ __forceinline__ ushort f2bf(float f) {
  union { float f; uint u; } v; v.f = f;
  uint r = v.u + 0x7fffu + ((v.u >> 16) & 1u);   // RNE
  return (ushort)(r >> 16);
}
__device__ __forceinline__ float bf_lo(uint u) {
  union { uint u; float f; } v; v.u = u << 16; return v.f;
}
__device__ __forceinline__ float bf_hi(uint u) {
  union { uint u; float f; } v; v.u = u & 0xffff0000u; return v.f;
}
__device__ __forceinline__ float b2f(ushort u) {
  union { uint u; float f; } v; v.u = (uint)u << 16; return v.f;
}

// ---------- prep kernels (unchanged, verified R2-R17) ----------

__global__ __launch_bounds__(256) void transpose_planes_k(
    const float* __restrict__ pxy, const float* __restrict__ pyz,
    const float* __restrict__ pxz, ushort* __restrict__ out) {
  int plane = blockIdx.x >> 8;
  int h = blockIdx.x & 255;
  const float* src = (plane == 0) ? pxy : (plane == 1) ? pyz : pxz;
  int w = threadIdx.x;
  int p = (h << 8) + w;
  uint vals[16];
#pragma unroll
  for (int c = 0; c < 32; c += 2) {
    float f0 = src[(size_t)c * 65536 + p];
    float f1 = src[(size_t)(c + 1) * 65536 + p];
    vals[c >> 1] = (uint)f2bf(f0) | ((uint)f2bf(f1) << 16);
  }
  uint4* d4 = (uint4*)(out + (size_t)plane * PLANE_T_ELEMS + (size_t)p * 32);
#pragma unroll
  for (int i = 0; i < 4; ++i)
    d4[i] = make_uint4(vals[4 * i], vals[4 * i + 1], vals[4 * i + 2], vals[4 * i + 3]);
}

// G[x][y][z] -> fragment-ordered bf16 table (verified):
// byte off = (y*2+xh)*1024 + l*16 + j*2  ->  G[x= xh*16+(l&15)][y][z= (l>>4)*8+j]
__global__ __launch_bounds__(256) void prep_grb_k(const float* __restrict__ g,
                                                  ushort* __restrict__ grb) {
  int e = blockIdx.x * 256 + threadIdx.x;   // 0..32767
  int j = e & 7;
  int l = (e >> 3) & 63;
  int xh = (e >> 9) & 1;
  int y = e >> 10;
  int x = xh * 16 + (l & 15);
  int z = ((l >> 4) << 3) + j;
  grb[e] = f2bf(g[x * 1024 + y * 32 + z]);
}

// ---------- bilinear sampler, BATCHED issue: all 16 tap loads, then combines.
// Identical per-channel arithmetic and order as the R2-verified sampler -> bit-exact.
template <class F>
__device__ __forceinline__ void sample_plane_b(const ushort* __restrict__ bt,
                                               float gw, float gh, F store) {
  float fx = (gw + 1.0f) * 0.5f * 255.0f;
  float fy = (gh + 1.0f) * 0.5f * 255.0f;
  float fx0 = floorf(fx), fy0 = floorf(fy);
  float wx1 = fx - fx0, wy1 = fy - fy0;
  float wx0 = 1.0f - wx1, wy0 = 1.0f - wy1;
  int ix0 = (int)fx0, iy0 = (int)fy0;
  int ix1 = ix0 + 1, iy1 = iy0 + 1;
  bool vx0 = (ix0 >= 0) & (ix0 < 256);
  bool vx1 = (ix1 >= 0) & (ix1 < 256);
  bool vy0 = (iy0 >= 0) & (iy0 < 256);
  bool vy1 = (iy1 >= 0) & (iy1 < 256);
  float w00 = (vx0 & vy0) ? wx0 * wy0 : 0.0f;
  float w10 = (vx1 & vy0) ? wx1 * wy0 : 0.0f;
  float w01 = (vx0 & vy1) ? wx0 * wy1 : 0.0f;
  float w11 = (vx1 & vy1) ? wx1 * wy1 : 0.0f;
  int cx0 = min(max(ix0, 0), 255), cx1 = min(max(ix1, 0), 255);
  int cy0 = min(max(iy0, 0), 255), cy1 = min(max(iy1, 0), 255);
  uint o00 = (uint)(((cy0 << 8) + cx0) << 6);
  uint o10 = (uint)(((cy0 << 8) + cx1) << 6);
  uint o01 = (uint)(((cy1 << 8) + cx0) << 6);
  uint o11 = (uint)(((cy1 << 8) + cx1) << 6);
  const char* base = (const char*)bt;

  uint4 T[16];                       // all taps in flight: one latency round
#pragma unroll
  for (int i = 0; i < 4; ++i) {
    T[4 * i + 0] = *(const uint4*)(base + o00 + i * 16);
    T[4 * i + 1] = *(const uint4*)(base + o10 + i * 16);
    T[4 * i + 2] = *(const uint4*)(base + o01 + i * 16);
    T[4 * i + 3] = *(const uint4*)(base + o11 + i * 16);
  }
#pragma unroll
  for (int i = 0; i < 4; ++i) {
    int cc = i * 8;
    uint4 a = T[4 * i + 0], b = T[4 * i + 1];
    uint4 c = T[4 * i + 2], d = T[4 * i + 3];
    const uint* pa = (const uint*)&a; const uint* pb = (const uint*)&b;
    const uint* pc = (const uint*)&c; const uint* pd = (const uint*)&d;
#pragma unroll
    for (int j = 0; j < 4; ++j) {
      float v0 = w00 * bf_lo(pa[j]) + w10 * bf_lo(pb[j]) +
                 w01 * bf_lo(pc[j]) + w11 * bf_lo(pd[j]);
      float v1 = w00 * bf_hi(pa[j]) + w10 * bf_hi(pb[j]) +
                 w01 * bf_hi(pc[j]) + w11 * bf_hi(pd[j]);
      store(cc + 2 * j, v0);
      store(cc + 2 * j + 1, v1);
    }
  }
}

// fp32 scalar sampler (verified R1; fallback only)
template <class F>
__device__ __forceinline__ void sample_plane_f32(const float* __restrict__ bf,
                                                 float gw, float gh, F store) {
  float fx = (gw + 1.0f) * 0.5f * 255.0f;
  float fy = (gh + 1.0f) * 0.5f * 255.0f;
  float fx0 = floorf(fx), fy0 = floorf(fy);
  float wx1 = fx - fx0, wy1 = fy - fy0;
  float wx0 = 1.0f - wx1, wy0 = 1.0f - wy1;
  int ix0 = (int)fx0, iy0 = (int)fy0;
  int ix1 = ix0 + 1, iy1 = iy0 + 1;
  bool vx0 = (ix0 >= 0) & (ix0 < 256);
  bool vx1 = (ix1 >= 0) & (ix1 < 256);
  bool vy0 = (iy0 >= 0) & (iy0 < 256);
  bool vy1 = (iy1 >= 0) & (iy1 < 256);
  float w00 = (vx0 & vy0) ? wx0 * wy0 : 0.0f;
  float w10 = (vx1 & vy0) ? wx1 * wy0 : 0.0f;
  float w01 = (vx0 & vy1) ? wx0 * wy1 : 0.0f;
  float w11 = (vx1 & vy1) ? wx1 * wy1 : 0.0f;
  int cx0 = min(max(ix0, 0), 255), cx1 = min(max(ix1, 0), 255);
  int cy0 = min(max(iy0, 0), 255), cy1 = min(max(iy1, 0), 255);
  int o00 = (cy0 << 8) + cx0, o10 = (cy0 << 8) + cx1;
  int o01 = (cy1 << 8) + cx0, o11 = (cy1 << 8) + cx1;
#pragma unroll
  for (int c = 0; c < 32; ++c) {
    const float* base = bf + (size_t)c * 65536;
    float v = w00 * base[o00] + w10 * base[o10] + w01 * base[o01] + w11 * base[o11];
    store(c, v);
  }
}

// ---------- MFMA main kernel: R17 verbatim + waves_per_eu(4,4) register unlock ----------
__global__ __launch_bounds__(256)
__attribute__((amdgpu_waves_per_eu(4, 4)))
void tucker_mfma_k(
    const float* __restrict__ coords,
    const ushort* __restrict__ planes_t,
    const ushort* __restrict__ grb,
    float* __restrict__ out) {
  __shared__ ushort xy_s[128][36];   // 72B rows (R4/R7-proven)
  __shared__ ushort xz_s[128][40];   // 80B rows, 16B-aligned b128 slots
  __shared__ ushort yz_s[128][36];   // 72B rows
  __shared__ float part_s[4][128];   // per-wave y-partials

  int tid = threadIdx.x;
  int l = tid & 63;
  int wv = tid >> 6;       // wave owns y = wv*8 .. wv*8+7
  int s = l & 15;
  int kb = l >> 4;

  // ---- sampling: R14 split-by-half, batched tap issue ----
  int q = tid & 127;                 // point row in LDS
  int p = blockIdx.x * 128 + q;
  float c0c = coords[3 * p + 0] * (1.0f / 1.3f);
  float c1c = coords[3 * p + 1] * (1.0f / 1.3f);
  float c2c = coords[3 * p + 2] * (1.0f / 1.3f);

  if (tid < 128) {
    uint buf[16];
    auto pack = [&](int c, float v) {
      ushort h = f2bf(v);
      if (c & 1) buf[c >> 1] |= ((uint)h << 16);
      else buf[c >> 1] = (uint)h;
    };
    // xy: W<-x(c0), H<-y(c1)
    sample_plane_b(planes_t, c0c, c1c, pack);
    uint2* r2 = (uint2*)xy_s[q];
#pragma unroll
    for (int i = 0; i < 8; ++i) r2[i] = make_uint2(buf[2 * i], buf[2 * i + 1]);
    // yz: W<-y(c1), H<-z(c2)
    sample_plane_b(planes_t + (size_t)PLANE_T_ELEMS, c1c, c2c, pack);
    r2 = (uint2*)yz_s[q];
#pragma unroll
    for (int i = 0; i < 8; ++i) r2[i] = make_uint2(buf[2 * i], buf[2 * i + 1]);
  } else {
    uint buf[16];
    auto pack = [&](int c, float v) {
      ushort h = f2bf(v);
      if (c & 1) buf[c >> 1] |= ((uint)h << 16);
      else buf[c >> 1] = (uint)h;
    };
    // xz: W<-x(c0), H<-z(c2)
    sample_plane_b(planes_t + (size_t)2 * PLANE_T_ELEMS, c0c, c2c, pack);
    uint4* r4 = (uint4*)xz_s[q];
#pragma unroll
    for (int i = 0; i < 4; ++i)
      r4[i] = make_uint4(buf[4 * i], buf[4 * i + 1], buf[4 * i + 2], buf[4 * i + 3]);
  }

  // ---- wave's 16 G-fragments (asm keep-alive; budget now allows true pinning) ----
  const char* gb = (const char*)grb;
  uint lbase = (uint)l * 16;
  bf16x8 greg[8][2];
#pragma unroll
  for (int yl = 0; yl < 8; ++yl) {
#pragma unroll
    for (int h = 0; h < 2; ++h)
      greg[yl][h] =
          *(const bf16x8*)(gb + (uint)((wv * 8 + yl) * 2048 + h * 1024) + lbase);
  }
#pragma unroll
  for (int yl = 0; yl < 8; ++yl) {
    asm volatile("" : "+v"(greg[yl][0]));
    asm volatile("" : "+v"(greg[yl][1]));
  }
  __syncthreads();

  // ---- main loop: d = mfma(G, xz); acc += yz[y]*d  (R14-verified scheme) ----
  f32x4 zero = {0.f, 0.f, 0.f, 0.f};
#pragma unroll 2
  for (int t = 0; t < 8; ++t) {
    int pt = t * 16 + s;
    union BF { uint4 u; bf16x8 v; } bfrag;       // B = raw xz bf16 (zero prep)
    bfrag.u = *(const uint4*)(&xz_s[pt][0] + kb * 8);
    const ushort* yr = yz_s[pt];
    uint yp[4];
    yp[0] = *(const uint*)(yr + wv * 8 + 0);
    yp[1] = *(const uint*)(yr + wv * 8 + 2);
    yp[2] = *(const uint*)(yr + wv * 8 + 4);
    yp[3] = *(const uint*)(yr + wv * 8 + 6);

    f32x2 acc0 = {0.f, 0.f}, acc1 = {0.f, 0.f};
    f32x2 acc2 = {0.f, 0.f}, acc3 = {0.f, 0.f};
#pragma unroll
    for (int qq = 0; qq < 4; ++qq) {
#pragma unroll
      for (int par = 0; par < 2; ++par) {
        float yv = par ? bf_hi(yp[qq]) : bf_lo(yp[qq]);
        union D { f32x4 v; f32x2 h[2]; } d0, d1;
        d0.v = __builtin_amdgcn_mfma_f32_16x16x32_bf16(greg[2 * qq + par][0],
                                                       bfrag.v, zero, 0, 0, 0);
        d1.v = __builtin_amdgcn_mfma_f32_16x16x32_bf16(greg[2 * qq + par][1],
                                                       bfrag.v, zero, 0, 0, 0);
        f32x2 yvv = {yv, yv};
        acc0 += d0.h[0] * yvv;
        acc1 += d0.h[1] * yvv;
        acc2 += d1.h[0] * yvv;
        acc3 += d1.h[1] * yvv;
      }
    }

    // epilogue (R14-verified D-layout: row=x=kb*4+r, col=point=s)
    const uint* xyr = (const uint*)xy_s[pt];
    uint q0 = xyr[kb * 2], q1 = xyr[kb * 2 + 1];
    uint q2 = xyr[8 + kb * 2], q3 = xyr[8 + kb * 2 + 1];
    float v = acc0[0] * bf_lo(q0) + acc0[1] * bf_hi(q0)
            + acc1[0] * bf_lo(q1) + acc1[1] * bf_hi(q1)
            + acc2[0] * bf_lo(q2) + acc2[1] * bf_hi(q2)
            + acc3[0] * bf_lo(q3) + acc3[1] * bf_hi(q3);
    v += __shfl_xor(v, 16, 64);
    v += __shfl_xor(v, 32, 64);
    if (l < 16) part_s[wv][pt] = v;   // kb==0 lanes hold pt = t*16+s
  }
  __syncthreads();

  // cross-wave sum of y-partials (linear, exact partition of y=0..31)
  if (tid < 128)
    out[blockIdx.x * 128 + tid] =
        part_s[0][tid] + part_s[1][tid] + part_s[2][tid] + part_s[3][tid];
}

// ---------- fallback (no workspace): slow-but-correct ----------
__global__ __launch_bounds__(256) void tucker_small_k(
    const float* __restrict__ coords,
    const float* __restrict__ pxy, const float* __restrict__ pyz,
    const float* __restrict__ pxz, const float* __restrict__ g,
    float* __restrict__ out) {
  __shared__ float s_yz[256 * 33];
  int tid = threadIdx.x;
  int p = blockIdx.x * 256 + tid;
  float c0 = coords[3 * p + 0] / 1.3f;
  float c1 = coords[3 * p + 1] / 1.3f;
  float c2 = coords[3 * p + 2] / 1.3f;
  float xy[32], xz[32];
  float* yzrow = &s_yz[tid * 33];
  sample_plane_f32(pxy, c0, c1, [&](int c, float v) { xy[c] = v; });
  sample_plane_f32(pyz, c1, c2, [&](int c, float v) { yzrow[c] = v; });
  sample_plane_f32(pxz, c0, c2, [&](int c, float v) { xz[c] = v; });
  float acc = 0.0f;
  for (int y = 0; y < 32; ++y) {
    float yzv = yzrow[y];
    float accy = 0.0f;
#pragma unroll
    for (int z = 0; z < 32; ++z) {
      float t0 = 0.f, t1 = 0.f, t2 = 0.f, t3 = 0.f;
#pragma unroll
      for (int x = 0; x < 32; x += 4) {
        t0 = fmaf(g[(x + 0) * 1024 + y * 32 + z], xy[x + 0], t0);
        t1 = fmaf(g[(x + 1) * 1024 + y * 32 + z], xy[x + 1], t1);
        t2 = fmaf(g[(x + 2) * 1024 + y * 32 + z], xy[x + 2], t2);
        t3 = fmaf(g[(x + 3) * 1024 + y * 32 + z], xy[x + 3], t3);
      }
      accy = fmaf((t0 + t1) + (t2 + t3), xz[z], accy);
    }
    acc = fmaf(accy, yzv, acc);
  }
  out[p] = acc;
}

extern "C" void kernel_launch(void* const* d_in, const int* in_sizes, int n_in,
                              void* d_out, int out_size, void* d_ws, size_t ws_size,
                              hipStream_t stream) {
  const float* coords = (const float*)d_in[0];
  const float* pxy = (const float*)d_in[1];
  const float* pyz = (const float*)d_in[2];
  const float* pxz = (const float*)d_in[3];
  const float* g   = (const float*)d_in[4];
  float* out = (float*)d_out;

  if (ws_size >= WS_NEEDED) {
    ushort* planes_t = (ushort*)d_ws;
    ushort* grb = (ushort*)((char*)d_ws + WS_GRB_OFF);
    hipLaunchKernelGGL(transpose_planes_k, dim3(768), dim3(256), 0, stream,
                       pxy, pyz, pxz, planes_t);
    hipLaunchKernelGGL(prep_grb_k, dim3(128), dim3(256), 0, stream, g, grb);
    hipLaunchKernelGGL(tucker_mfma_k, dim3(NPTS / 128), dim3(256), 0, stream,
                       coords, planes_t, grb, out);
  } else {
    hipLaunchKernelGGL(tucker_small_k, dim3(NPTS / 256), dim3(256), 0, stream,
                       coords, pxy, pyz, pxz, g, out);
  }
}

// Round 19
// 53.113 us; speedup vs baseline: 2.6545x; 1.0946x over previous
//
#include <hip/hip_runtime.h>
#include <stdint.h>

typedef unsigned int uint;
typedef unsigned short ushort;

#define NPTS  262144
#define PLANE_T_ELEMS (65536 * 32)
#define PLANE_T_BYTES ((size_t)PLANE_T_ELEMS * 2)
#define WS_PLANES_BYTES ((size_t)3 * PLANE_T_ELEMS * 2)   // 12582912
#define WS_GRB_OFF  WS_PLANES_BYTES
#define WS_NEEDED   (WS_PLANES_BYTES + (size_t)32768 * 2)

typedef __attribute__((ext_vector_type(8))) short bf16x8;   // 8 bf16 = 4 VGPR
typedef __attribute__((ext_vector_type(4))) float f32x4;
typedef __attribute__((ext_vector_type(2))) float f32x2;

__device__ __forceinline__ ushort f2bf(float f) {
  union { float f; uint u; } v; v.f = f;
  uint r = v.u + 0x7fffu + ((v.u >> 16) & 1u);   // RNE
  return (ushort)(r >> 16);
}
__device__ __forceinline__ float bf_lo(uint u) {
  union { uint u; float f; } v; v.u = u << 16; return v.f;
}
__device__ __forceinline__ float bf_hi(uint u) {
  union { uint u; float f; } v; v.u = u & 0xffff0000u; return v.f;
}
__device__ __forceinline__ float b2f(ushort u) {
  union { uint u; float f; } v; v.u = (uint)u << 16; return v.f;
}

// 4 x 16B loads from one tap base, offsets folded; outputs pinned by volatile asm
__device__ __forceinline__ void gl4(const char* a, uint4& r0, uint4& r1,
                                    uint4& r2, uint4& r3) {
  asm volatile(
      "global_load_dwordx4 %0, %4, off\n\t"
      "global_load_dwordx4 %1, %4, off offset:16\n\t"
      "global_load_dwordx4 %2, %4, off offset:32\n\t"
      "global_load_dwordx4 %3, %4, off offset:48"
      : "=&v"(r0), "=&v"(r1), "=&v"(r2), "=&v"(r3)
      : "v"(a));
}

// ---------- prep kernels (unchanged, verified R2-R18) ----------

__global__ __launch_bounds__(256) void transpose_planes_k(
    const float* __restrict__ pxy, const float* __restrict__ pyz,
    const float* __restrict__ pxz, ushort* __restrict__ out) {
  int plane = blockIdx.x >> 8;
  int h = blockIdx.x & 255;
  const float* src = (plane == 0) ? pxy : (plane == 1) ? pyz : pxz;
  int w = threadIdx.x;
  int p = (h << 8) + w;
  uint vals[16];
#pragma unroll
  for (int c = 0; c < 32; c += 2) {
    float f0 = src[(size_t)c * 65536 + p];
    float f1 = src[(size_t)(c + 1) * 65536 + p];
    vals[c >> 1] = (uint)f2bf(f0) | ((uint)f2bf(f1) << 16);
  }
  uint4* d4 = (uint4*)(out + (size_t)plane * PLANE_T_ELEMS + (size_t)p * 32);
#pragma unroll
  for (int i = 0; i < 4; ++i)
    d4[i] = make_uint4(vals[4 * i], vals[4 * i + 1], vals[4 * i + 2], vals[4 * i + 3]);
}

// G[x][y][z] -> fragment-ordered bf16 table (verified):
// byte off = (y*2+xh)*1024 + l*16 + j*2  ->  G[x= xh*16+(l&15)][y][z= (l>>4)*8+j]
__global__ __launch_bounds__(256) void prep_grb_k(const float* __restrict__ g,
                                                  ushort* __restrict__ grb) {
  int e = blockIdx.x * 256 + threadIdx.x;   // 0..32767
  int j = e & 7;
  int l = (e >> 3) & 63;
  int xh = (e >> 9) & 1;
  int y = e >> 10;
  int x = xh * 16 + (l & 15);
  int z = ((l >> 4) << 3) + j;
  grb[e] = f2bf(g[x * 1024 + y * 32 + z]);
}

// ---------- bilinear sampler: asm-batched taps (1 latency round), then combines.
// Identical per-channel arithmetic and order as the R2-verified sampler -> bit-exact.
template <class F>
__device__ __forceinline__ void sample_plane_b(const ushort* __restrict__ bt,
                                               float gw, float gh, F store) {
  float fx = (gw + 1.0f) * 0.5f * 255.0f;
  float fy = (gh + 1.0f) * 0.5f * 255.0f;
  float fx0 = floorf(fx), fy0 = floorf(fy);
  float wx1 = fx - fx0, wy1 = fy - fy0;
  float wx0 = 1.0f - wx1, wy0 = 1.0f - wy1;
  int ix0 = (int)fx0, iy0 = (int)fy0;
  int ix1 = ix0 + 1, iy1 = iy0 + 1;
  bool vx0 = (ix0 >= 0) & (ix0 < 256);
  bool vx1 = (ix1 >= 0) & (ix1 < 256);
  bool vy0 = (iy0 >= 0) & (iy0 < 256);
  bool vy1 = (iy1 >= 0) & (iy1 < 256);
  float w00 = (vx0 & vy0) ? wx0 * wy0 : 0.0f;
  float w10 = (vx1 & vy0) ? wx1 * wy0 : 0.0f;
  float w01 = (vx0 & vy1) ? wx0 * wy1 : 0.0f;
  float w11 = (vx1 & vy1) ? wx1 * wy1 : 0.0f;
  int cx0 = min(max(ix0, 0), 255), cx1 = min(max(ix1, 0), 255);
  int cy0 = min(max(iy0, 0), 255), cy1 = min(max(iy1, 0), 255);
  uint o00 = (uint)(((cy0 << 8) + cx0) << 6);
  uint o10 = (uint)(((cy0 << 8) + cx1) << 6);
  uint o01 = (uint)(((cy1 << 8) + cx0) << 6);
  uint o11 = (uint)(((cy1 << 8) + cx1) << 6);
  const char* base = (const char*)bt;

  uint4 T[16];                       // ALL taps in flight: one latency round
  gl4(base + o00, T[0], T[4], T[8], T[12]);
  gl4(base + o10, T[1], T[5], T[9], T[13]);
  gl4(base + o01, T[2], T[6], T[10], T[14]);
  gl4(base + o11, T[3], T[7], T[11], T[15]);
  asm volatile("s_waitcnt vmcnt(0)" ::: "memory");
  __builtin_amdgcn_sched_barrier(0);   // combines must not hoist above the wait

#pragma unroll
  for (int i = 0; i < 4; ++i) {
    int cc = i * 8;
    uint4 a = T[4 * i + 0], b = T[4 * i + 1];
    uint4 c = T[4 * i + 2], d = T[4 * i + 3];
    const uint* pa = (const uint*)&a; const uint* pb = (const uint*)&b;
    const uint* pc = (const uint*)&c; const uint* pd = (const uint*)&d;
#pragma unroll
    for (int j = 0; j < 4; ++j) {
      float v0 = w00 * bf_lo(pa[j]) + w10 * bf_lo(pb[j]) +
                 w01 * bf_lo(pc[j]) + w11 * bf_lo(pd[j]);
      float v1 = w00 * bf_hi(pa[j]) + w10 * bf_hi(pb[j]) +
                 w01 * bf_hi(pc[j]) + w11 * bf_hi(pd[j]);
      store(cc + 2 * j, v0);
      store(cc + 2 * j + 1, v1);
    }
  }
}

// fp32 scalar sampler (verified R1; fallback only)
template <class F>
__device__ __forceinline__ void sample_plane_f32(const float* __restrict__ bf,
                                                 float gw, float gh, F store) {
  float fx = (gw + 1.0f) * 0.5f * 255.0f;
  float fy = (gh + 1.0f) * 0.5f * 255.0f;
  float fx0 = floorf(fx), fy0 = floorf(fy);
  float wx1 = fx - fx0, wy1 = fy - fy0;
  float wx0 = 1.0f - wx1, wy0 = 1.0f - wy1;
  int ix0 = (int)fx0, iy0 = (int)fy0;
  int ix1 = ix0 + 1, iy1 = iy0 + 1;
  bool vx0 = (ix0 >= 0) & (ix0 < 256);
  bool vx1 = (ix1 >= 0) & (ix1 < 256);
  bool vy0 = (iy0 >= 0) & (iy0 < 256);
  bool vy1 = (iy1 >= 0) & (iy1 < 256);
  float w00 = (vx0 & vy0) ? wx0 * wy0 : 0.0f;
  float w10 = (vx1 & vy0) ? wx1 * wy0 : 0.0f;
  float w01 = (vx0 & vy1) ? wx0 * wy1 : 0.0f;
  float w11 = (vx1 & vy1) ? wx1 * wy1 : 0.0f;
  int cx0 = min(max(ix0, 0), 255), cx1 = min(max(ix1, 0), 255);
  int cy0 = min(max(iy0, 0), 255), cy1 = min(max(iy1, 0), 255);
  int o00 = (cy0 << 8) + cx0, o10 = (cy0 << 8) + cx1;
  int o01 = (cy1 << 8) + cx0, o11 = (cy1 << 8) + cx1;
#pragma unroll
  for (int c = 0; c < 32; ++c) {
    const float* base = bf + (size_t)c * 65536;
    float v = w00 * base[o00] + w10 * base[o10] + w01 * base[o01] + w11 * base[o11];
    store(c, v);
  }
}

// ---------- MFMA main kernel: R18 structure, asm-batched gather ----------
__global__ __launch_bounds__(256)
__attribute__((amdgpu_waves_per_eu(4, 4)))
void tucker_mfma_k(
    const float* __restrict__ coords,
    const ushort* __restrict__ planes_t,
    const ushort* __restrict__ grb,
    float* __restrict__ out) {
  __shared__ ushort xy_s[128][36];   // 72B rows (R4/R7-proven)
  __shared__ ushort xz_s[128][40];   // 80B rows, 16B-aligned b128 slots
  __shared__ ushort yz_s[128][36];   // 72B rows
  __shared__ float part_s[4][128];   // per-wave y-partials

  int tid = threadIdx.x;
  int l = tid & 63;
  int wv = tid >> 6;       // wave owns y = wv*8 .. wv*8+7
  int s = l & 15;
  int kb = l >> 4;

  // ---- sampling: R14 split-by-half, asm-batched tap issue ----
  int q = tid & 127;                 // point row in LDS
  int p = blockIdx.x * 128 + q;
  float c0c = coords[3 * p + 0] * (1.0f / 1.3f);
  float c1c = coords[3 * p + 1] * (1.0f / 1.3f);
  float c2c = coords[3 * p + 2] * (1.0f / 1.3f);

  if (tid < 128) {
    uint buf[16];
    auto pack = [&](int c, float v) {
      ushort h = f2bf(v);
      if (c & 1) buf[c >> 1] |= ((uint)h << 16);
      else buf[c >> 1] = (uint)h;
    };
    // xy: W<-x(c0), H<-y(c1)
    sample_plane_b(planes_t, c0c, c1c, pack);
    uint2* r2 = (uint2*)xy_s[q];
#pragma unroll
    for (int i = 0; i < 8; ++i) r2[i] = make_uint2(buf[2 * i], buf[2 * i + 1]);
    // yz: W<-y(c1), H<-z(c2)
    sample_plane_b(planes_t + (size_t)PLANE_T_ELEMS, c1c, c2c, pack);
    r2 = (uint2*)yz_s[q];
#pragma unroll
    for (int i = 0; i < 8; ++i) r2[i] = make_uint2(buf[2 * i], buf[2 * i + 1]);
  } else {
    uint buf[16];
    auto pack = [&](int c, float v) {
      ushort h = f2bf(v);
      if (c & 1) buf[c >> 1] |= ((uint)h << 16);
      else buf[c >> 1] = (uint)h;
    };
    // xz: W<-x(c0), H<-z(c2)
    sample_plane_b(planes_t + (size_t)2 * PLANE_T_ELEMS, c0c, c2c, pack);
    uint4* r4 = (uint4*)xz_s[q];
#pragma unroll
    for (int i = 0; i < 4; ++i)
      r4[i] = make_uint4(buf[4 * i], buf[4 * i + 1], buf[4 * i + 2], buf[4 * i + 3]);
  }

  // ---- wave's 16 G-fragments (asm keep-alive; compiler may still reload) ----
  const char* gb = (const char*)grb;
  uint lbase = (uint)l * 16;
  bf16x8 greg[8][2];
#pragma unroll
  for (int yl = 0; yl < 8; ++yl) {
#pragma unroll
    for (int h = 0; h < 2; ++h)
      greg[yl][h] =
          *(const bf16x8*)(gb + (uint)((wv * 8 + yl) * 2048 + h * 1024) + lbase);
  }
#pragma unroll
  for (int yl = 0; yl < 8; ++yl) {
    asm volatile("" : "+v"(greg[yl][0]));
    asm volatile("" : "+v"(greg[yl][1]));
  }
  __syncthreads();

  // ---- main loop: d = mfma(G, xz); acc += yz[y]*d  (R14-verified scheme) ----
  f32x4 zero = {0.f, 0.f, 0.f, 0.f};
#pragma unroll 2
  for (int t = 0; t < 8; ++t) {
    int pt = t * 16 + s;
    union BF { uint4 u; bf16x8 v; } bfrag;       // B = raw xz bf16 (zero prep)
    bfrag.u = *(const uint4*)(&xz_s[pt][0] + kb * 8);
    const ushort* yr = yz_s[pt];
    uint yp[4];
    yp[0] = *(const uint*)(yr + wv * 8 + 0);
    yp[1] = *(const uint*)(yr + wv * 8 + 2);
    yp[2] = *(const uint*)(yr + wv * 8 + 4);
    yp[3] = *(const uint*)(yr + wv * 8 + 6);

    f32x2 acc0 = {0.f, 0.f}, acc1 = {0.f, 0.f};
    f32x2 acc2 = {0.f, 0.f}, acc3 = {0.f, 0.f};
#pragma unroll
    for (int qq = 0; qq < 4; ++qq) {
#pragma unroll
      for (int par = 0; par < 2; ++par) {
        float yv = par ? bf_hi(yp[qq]) : bf_lo(yp[qq]);
        union D { f32x4 v; f32x2 h[2]; } d0, d1;
        d0.v = __builtin_amdgcn_mfma_f32_16x16x32_bf16(greg[2 * qq + par][0],
                                                       bfrag.v, zero, 0, 0, 0);
        d1.v = __builtin_amdgcn_mfma_f32_16x16x32_bf16(greg[2 * qq + par][1],
                                                       bfrag.v, zero, 0, 0, 0);
        f32x2 yvv = {yv, yv};
        acc0 += d0.h[0] * yvv;
        acc1 += d0.h[1] * yvv;
        acc2 += d1.h[0] * yvv;
        acc3 += d1.h[1] * yvv;
      }
    }

    // epilogue (R14-verified D-layout: row=x=kb*4+r, col=point=s)
    const uint* xyr = (const uint*)xy_s[pt];
    uint q0 = xyr[kb * 2], q1 = xyr[kb * 2 + 1];
    uint q2 = xyr[8 + kb * 2], q3 = xyr[8 + kb * 2 + 1];
    float v = acc0[0] * bf_lo(q0) + acc0[1] * bf_hi(q0)
            + acc1[0] * bf_lo(q1) + acc1[1] * bf_hi(q1)
            + acc2[0] * bf_lo(q2) + acc2[1] * bf_hi(q2)
            + acc3[0] * bf_lo(q3) + acc3[1] * bf_hi(q3);
    v += __shfl_xor(v, 16, 64);
    v += __shfl_xor(v, 32, 64);
    if (l < 16) part_s[wv][pt] = v;   // kb==0 lanes hold pt = t*16+s
  }
  __syncthreads();

  // cross-wave sum of y-partials (linear, exact partition of y=0..31)
  if (tid < 128)
    out[blockIdx.x * 128 + tid] =
        part_s[0][tid] + part_s[1][tid] + part_s[2][tid] + part_s[3][tid];
}

// ---------- fallback (no workspace): slow-but-correct ----------
__global__ __launch_bounds__(256) void tucker_small_k(
    const float* __restrict__ coords,
    const float* __restrict__ pxy, const float* __restrict__ pyz,
    const float* __restrict__ pxz, const float* __restrict__ g,
    float* __restrict__ out) {
  __shared__ float s_yz[256 * 33];
  int tid = threadIdx.x;
  int p = blockIdx.x * 256 + tid;
  float c0 = coords[3 * p + 0] / 1.3f;
  float c1 = coords[3 * p + 1] / 1.3f;
  float c2 = coords[3 * p + 2] / 1.3f;
  float xy[32], xz[32];
  float* yzrow = &s_yz[tid * 33];
  sample_plane_f32(pxy, c0, c1, [&](int c, float v) { xy[c] = v; });
  sample_plane_f32(pyz, c1, c2, [&](int c, float v) { yzrow[c] = v; });
  sample_plane_f32(pxz, c0, c2, [&](int c, float v) { xz[c] = v; });
  float acc = 0.0f;
  for (int y = 0; y < 32; ++y) {
    float yzv = yzrow[y];
    float accy = 0.0f;
#pragma unroll
    for (int z = 0; z < 32; ++z) {
      float t0 = 0.f, t1 = 0.f, t2 = 0.f, t3 = 0.f;
#pragma unroll
      for (int x = 0; x < 32; x += 4) {
        t0 = fmaf(g[(x + 0) * 1024 + y * 32 + z], xy[x + 0], t0);
        t1 = fmaf(g[(x + 1) * 1024 + y * 32 + z], xy[x + 1], t1);
        t2 = fmaf(g[(x + 2) * 1024 + y * 32 + z], xy[x + 2], t2);
        t3 = fmaf(g[(x + 3) * 1024 + y * 32 + z], xy[x + 3], t3);
      }
      accy = fmaf((t0 + t1) + (t2 + t3), xz[z], accy);
    }
    acc = fmaf(accy, yzv, acc);
  }
  out[p] = acc;
}

extern "C" void kernel_launch(void* const* d_in, const int* in_sizes, int n_in,
                              void* d_out, int out_size, void* d_ws, size_t ws_size,
                              hipStream_t stream) {
  const float* coords = (const float*)d_in[0];
  const float* pxy = (const float*)d_in[1];
  const float* pyz = (const float*)d_in[2];
  const float* pxz = (const float*)d_in[3];
  const float* g   = (const float*)d_in[4];
  float* out = (float*)d_out;

  if (ws_size >= WS_NEEDED) {
    ushort* planes_t = (ushort*)d_ws;
    ushort* grb = (ushort*)((char*)d_ws + WS_GRB_OFF);
    hipLaunchKernelGGL(transpose_planes_k, dim3(768), dim3(256), 0, stream,
                       pxy, pyz, pxz, planes_t);
    hipLaunchKernelGGL(prep_grb_k, dim3(128), dim3(256), 0, stream, g, grb);
    hipLaunchKernelGGL(tucker_mfma_k, dim3(NPTS / 128), dim3(256), 0, stream,
                       coords, planes_t, grb, out);
  } else {
    hipLaunchKernelGGL(tucker_small_k, dim3(NPTS / 256), dim3(256), 0, stream,
                       coords, pxy, pyz, pxz, g, out);
  }
}

// Round 20
// 52.848 us; speedup vs baseline: 2.6679x; 1.0050x over previous
//
#include <hip/hip_runtime.h>
#include <stdint.h>

typedef unsigned int uint;
typedef unsigned short ushort;

#define NPTS  262144
#define PLANE_T_ELEMS (65536 * 32)
#define PLANE_T_BYTES ((size_t)PLANE_T_ELEMS * 2)
#define WS_PLANES_BYTES ((size_t)3 * PLANE_T_ELEMS * 2)   // 12582912
#define WS_GRB_OFF  WS_PLANES_BYTES
#define WS_NEEDED   (WS_PLANES_BYTES + (size_t)32768 * 2)

typedef __attribute__((ext_vector_type(8))) short bf16x8;   // 8 bf16 = 4 VGPR
typedef __attribute__((ext_vector_type(4))) float f32x4;
typedef __attribute__((ext_vector_type(2))) float f32x2;

__device__ __forceinline__ ushort f2bf(float f) {
  union { float f; uint u; } v; v.f = f;
  uint r = v.u + 0x7fffu + ((v.u >> 16) & 1u);   // RNE
  return (ushort)(r >> 16);
}
__device__ __forceinline__ float bf_lo(uint u) {
  union { uint u; float f; } v; v.u = u << 16; return v.f;
}
__device__ __forceinline__ float bf_hi(uint u) {
  union { uint u; float f; } v; v.u = u & 0xffff0000u; return v.f;
}
__device__ __forceinline__ float b2f(ushort u) {
  union { uint u; float f; } v; v.u = (uint)u << 16; return v.f;
}

// 4 x 16B loads from one tap base, offsets folded; outputs pinned by volatile asm
__device__ __forceinline__ void gl4(const char* a, uint4& r0, uint4& r1,
                                    uint4& r2, uint4& r3) {
  asm volatile(
      "global_load_dwordx4 %0, %4, off\n\t"
      "global_load_dwordx4 %1, %4, off offset:16\n\t"
      "global_load_dwordx4 %2, %4, off offset:32\n\t"
      "global_load_dwordx4 %3, %4, off offset:48"
      : "=&v"(r0), "=&v"(r1), "=&v"(r2), "=&v"(r3)
      : "v"(a));
}

// ---------- prep kernels (unchanged, verified R2-R19) ----------

__global__ __launch_bounds__(256) void transpose_planes_k(
    const float* __restrict__ pxy, const float* __restrict__ pyz,
    const float* __restrict__ pxz, ushort* __restrict__ out) {
  int plane = blockIdx.x >> 8;
  int h = blockIdx.x & 255;
  const float* src = (plane == 0) ? pxy : (plane == 1) ? pyz : pxz;
  int w = threadIdx.x;
  int p = (h << 8) + w;
  uint vals[16];
#pragma unroll
  for (int c = 0; c < 32; c += 2) {
    float f0 = src[(size_t)c * 65536 + p];
    float f1 = src[(size_t)(c + 1) * 65536 + p];
    vals[c >> 1] = (uint)f2bf(f0) | ((uint)f2bf(f1) << 16);
  }
  uint4* d4 = (uint4*)(out + (size_t)plane * PLANE_T_ELEMS + (size_t)p * 32);
#pragma unroll
  for (int i = 0; i < 4; ++i)
    d4[i] = make_uint4(vals[4 * i], vals[4 * i + 1], vals[4 * i + 2], vals[4 * i + 3]);
}

// G[x][y][z] -> fragment-ordered bf16 table (verified):
// byte off = (y*2+xh)*1024 + l*16 + j*2  ->  G[x= xh*16+(l&15)][y][z= (l>>4)*8+j]
__global__ __launch_bounds__(256) void prep_grb_k(const float* __restrict__ g,
                                                  ushort* __restrict__ grb) {
  int e = blockIdx.x * 256 + threadIdx.x;   // 0..32767
  int j = e & 7;
  int l = (e >> 3) & 63;
  int xh = (e >> 9) & 1;
  int y = e >> 10;
  int x = xh * 16 + (l & 15);
  int z = ((l >> 4) << 3) + j;
  grb[e] = f2bf(g[x * 1024 + y * 32 + z]);
}

// ---------- bilinear weights/offsets (identical arithmetic to verified sampler) ----------
struct WO { float w00, w10, w01, w11; uint o00, o10, o01, o11; };
__device__ __forceinline__ WO plane_wo(float gw, float gh) {
  float fx = (gw + 1.0f) * 0.5f * 255.0f;
  float fy = (gh + 1.0f) * 0.5f * 255.0f;
  float fx0 = floorf(fx), fy0 = floorf(fy);
  float wx1 = fx - fx0, wy1 = fy - fy0;
  float wx0 = 1.0f - wx1, wy0 = 1.0f - wy1;
  int ix0 = (int)fx0, iy0 = (int)fy0;
  int ix1 = ix0 + 1, iy1 = iy0 + 1;
  bool vx0 = (ix0 >= 0) & (ix0 < 256);
  bool vx1 = (ix1 >= 0) & (ix1 < 256);
  bool vy0 = (iy0 >= 0) & (iy0 < 256);
  bool vy1 = (iy1 >= 0) & (iy1 < 256);
  WO r;
  r.w00 = (vx0 & vy0) ? wx0 * wy0 : 0.0f;
  r.w10 = (vx1 & vy0) ? wx1 * wy0 : 0.0f;
  r.w01 = (vx0 & vy1) ? wx0 * wy1 : 0.0f;
  r.w11 = (vx1 & vy1) ? wx1 * wy1 : 0.0f;
  int cx0 = min(max(ix0, 0), 255), cx1 = min(max(ix1, 0), 255);
  int cy0 = min(max(iy0, 0), 255), cy1 = min(max(iy1, 0), 255);
  r.o00 = (uint)(((cy0 << 8) + cx0) << 6);
  r.o10 = (uint)(((cy0 << 8) + cx1) << 6);
  r.o01 = (uint)(((cy1 << 8) + cx0) << 6);
  r.o11 = (uint)(((cy1 << 8) + cx1) << 6);
  return r;
}

// combine 16 taps -> 32 bf16 channels, write as 8 uint2 (identical math/order)
__device__ __forceinline__ void combine16(const uint4* T, float w00, float w10,
                                          float w01, float w11, ushort* dst) {
  uint buf[16];
#pragma unroll
  for (int i = 0; i < 4; ++i) {
    uint4 a = T[4 * i + 0], b = T[4 * i + 1];
    uint4 c = T[4 * i + 2], d = T[4 * i + 3];
    const uint* pa = (const uint*)&a; const uint* pb = (const uint*)&b;
    const uint* pc = (const uint*)&c; const uint* pd = (const uint*)&d;
#pragma unroll
    for (int j = 0; j < 4; ++j) {
      float v0 = w00 * bf_lo(pa[j]) + w10 * bf_lo(pb[j]) +
                 w01 * bf_lo(pc[j]) + w11 * bf_lo(pd[j]);
      float v1 = w00 * bf_hi(pa[j]) + w10 * bf_hi(pb[j]) +
                 w01 * bf_hi(pc[j]) + w11 * bf_hi(pd[j]);
      buf[4 * i + j] = (uint)f2bf(v0) | ((uint)f2bf(v1) << 16);
    }
  }
  uint2* r2 = (uint2*)dst;
#pragma unroll
  for (int i = 0; i < 8; ++i) r2[i] = make_uint2(buf[2 * i], buf[2 * i + 1]);
}

// single-plane asm-batched sampler (R19-verified) — used for the xz half
template <class F>
__device__ __forceinline__ void sample_plane_b(const ushort* __restrict__ bt,
                                               float gw, float gh, F store) {
  WO w = plane_wo(gw, gh);
  const char* base = (const char*)bt;
  uint4 T[16];
  gl4(base + w.o00, T[0], T[4], T[8], T[12]);
  gl4(base + w.o10, T[1], T[5], T[9], T[13]);
  gl4(base + w.o01, T[2], T[6], T[10], T[14]);
  gl4(base + w.o11, T[3], T[7], T[11], T[15]);
  asm volatile("s_waitcnt vmcnt(0)" ::: "memory");
  __builtin_amdgcn_sched_barrier(0);
#pragma unroll
  for (int i = 0; i < 4; ++i) {
    int cc = i * 8;
    uint4 a = T[4 * i + 0], b = T[4 * i + 1];
    uint4 c = T[4 * i + 2], d = T[4 * i + 3];
    const uint* pa = (const uint*)&a; const uint* pb = (const uint*)&b;
    const uint* pc = (const uint*)&c; const uint* pd = (const uint*)&d;
#pragma unroll
    for (int j = 0; j < 4; ++j) {
      float v0 = w.w00 * bf_lo(pa[j]) + w.w10 * bf_lo(pb[j]) +
                 w.w01 * bf_lo(pc[j]) + w.w11 * bf_lo(pd[j]);
      float v1 = w.w00 * bf_hi(pa[j]) + w.w10 * bf_hi(pb[j]) +
                 w.w01 * bf_hi(pc[j]) + w.w11 * bf_hi(pd[j]);
      store(cc + 2 * j, v0);
      store(cc + 2 * j + 1, v1);
    }
  }
}

// fp32 scalar sampler (verified R1; fallback only)
template <class F>
__device__ __forceinline__ void sample_plane_f32(const float* __restrict__ bf,
                                                 float gw, float gh, F store) {
  WO w = plane_wo(gw, gh);
  int o00 = (int)(w.o00 >> 6), o10 = (int)(w.o10 >> 6);
  int o01 = (int)(w.o01 >> 6), o11 = (int)(w.o11 >> 6);
#pragma unroll
  for (int c = 0; c < 32; ++c) {
    const float* base = bf + (size_t)c * 65536;
    float v = w.w00 * base[o00] + w.w10 * base[o10] +
              w.w01 * base[o01] + w.w11 * base[o11];
    store(c, v);
  }
}

// ---------- MFMA main kernel: R19 + dual-plane counted-vmcnt gather ----------
__global__ __launch_bounds__(256)
__attribute__((amdgpu_waves_per_eu(3, 4)))
void tucker_mfma_k(
    const float* __restrict__ coords,
    const ushort* __restrict__ planes_t,
    const ushort* __restrict__ grb,
    float* __restrict__ out) {
  __shared__ ushort xy_s[128][36];   // 72B rows (R4/R7-proven)
  __shared__ ushort xz_s[128][40];   // 80B rows, 16B-aligned b128 slots
  __shared__ ushort yz_s[128][36];   // 72B rows
  __shared__ float part_s[4][128];   // per-wave y-partials

  int tid = threadIdx.x;
  int l = tid & 63;
  int wv = tid >> 6;       // wave owns y = wv*8 .. wv*8+7
  int s = l & 15;
  int kb = l >> 4;

  // ---- sampling ----
  int q = tid & 127;                 // point row in LDS
  int p = blockIdx.x * 128 + q;
  float c0c = coords[3 * p + 0] * (1.0f / 1.3f);
  float c1c = coords[3 * p + 1] * (1.0f / 1.3f);
  float c2c = coords[3 * p + 2] * (1.0f / 1.3f);

  if (tid < 128) {
    // both planes' 32 taps in flight; counted vmcnt overlaps yz's latency
    WO wa = plane_wo(c0c, c1c);          // xy: W<-x(c0), H<-y(c1)
    WO wb = plane_wo(c1c, c2c);          // yz: W<-y(c1), H<-z(c2)
    const char* b0 = (const char*)planes_t;
    const char* b1 = b0 + PLANE_T_BYTES;
    uint4 TA[16], TB[16];
    gl4(b0 + wa.o00, TA[0], TA[4], TA[8], TA[12]);
    gl4(b0 + wa.o10, TA[1], TA[5], TA[9], TA[13]);
    gl4(b0 + wa.o01, TA[2], TA[6], TA[10], TA[14]);
    gl4(b0 + wa.o11, TA[3], TA[7], TA[11], TA[15]);
    gl4(b1 + wb.o00, TB[0], TB[4], TB[8], TB[12]);
    gl4(b1 + wb.o10, TB[1], TB[5], TB[9], TB[13]);
    gl4(b1 + wb.o01, TB[2], TB[6], TB[10], TB[14]);
    gl4(b1 + wb.o11, TB[3], TB[7], TB[11], TB[15]);
    asm volatile("s_waitcnt vmcnt(16)" ::: "memory");   // xy's 16 (oldest) done
    __builtin_amdgcn_sched_barrier(0);
    combine16(TA, wa.w00, wa.w10, wa.w01, wa.w11, xy_s[q]);
    asm volatile("s_waitcnt vmcnt(0)" ::: "memory");    // yz done (latency hidden)
    __builtin_amdgcn_sched_barrier(0);
    combine16(TB, wb.w00, wb.w10, wb.w01, wb.w11, yz_s[q]);
  } else {
    uint buf[16];
    auto pack = [&](int c, float v) {
      ushort h = f2bf(v);
      if (c & 1) buf[c >> 1] |= ((uint)h << 16);
      else buf[c >> 1] = (uint)h;
    };
    // xz: W<-x(c0), H<-z(c2)  (R19-verified single-round path)
    sample_plane_b(planes_t + (size_t)2 * PLANE_T_ELEMS, c0c, c2c, pack);
    uint4* r4 = (uint4*)xz_s[q];
#pragma unroll
    for (int i = 0; i < 4; ++i)
      r4[i] = make_uint4(buf[4 * i], buf[4 * i + 1], buf[4 * i + 2], buf[4 * i + 3]);
  }

  // ---- wave's 16 G-fragments (asm keep-alive) ----
  const char* gb = (const char*)grb;
  uint lbase = (uint)l * 16;
  bf16x8 greg[8][2];
#pragma unroll
  for (int yl = 0; yl < 8; ++yl) {
#pragma unroll
    for (int h = 0; h < 2; ++h)
      greg[yl][h] =
          *(const bf16x8*)(gb + (uint)((wv * 8 + yl) * 2048 + h * 1024) + lbase);
  }
#pragma unroll
  for (int yl = 0; yl < 8; ++yl) {
    asm volatile("" : "+v"(greg[yl][0]));
    asm volatile("" : "+v"(greg[yl][1]));
  }
  __syncthreads();

  // ---- main loop: d = mfma(G, xz); acc += yz[y]*d  (R14-verified scheme) ----
  f32x4 zero = {0.f, 0.f, 0.f, 0.f};
#pragma unroll 2
  for (int t = 0; t < 8; ++t) {
    int pt = t * 16 + s;
    union BF { uint4 u; bf16x8 v; } bfrag;       // B = raw xz bf16 (zero prep)
    bfrag.u = *(const uint4*)(&xz_s[pt][0] + kb * 8);
    const ushort* yr = yz_s[pt];
    uint yp[4];
    yp[0] = *(const uint*)(yr + wv * 8 + 0);
    yp[1] = *(const uint*)(yr + wv * 8 + 2);
    yp[2] = *(const uint*)(yr + wv * 8 + 4);
    yp[3] = *(const uint*)(yr + wv * 8 + 6);

    f32x2 acc0 = {0.f, 0.f}, acc1 = {0.f, 0.f};
    f32x2 acc2 = {0.f, 0.f}, acc3 = {0.f, 0.f};
#pragma unroll
    for (int qq = 0; qq < 4; ++qq) {
#pragma unroll
      for (int par = 0; par < 2; ++par) {
        float yv = par ? bf_hi(yp[qq]) : bf_lo(yp[qq]);
        union D { f32x4 v; f32x2 h[2]; } d0, d1;
        d0.v = __builtin_amdgcn_mfma_f32_16x16x32_bf16(greg[2 * qq + par][0],
                                                       bfrag.v, zero, 0, 0, 0);
        d1.v = __builtin_amdgcn_mfma_f32_16x16x32_bf16(greg[2 * qq + par][1],
                                                       bfrag.v, zero, 0, 0, 0);
        f32x2 yvv = {yv, yv};
        acc0 += d0.h[0] * yvv;
        acc1 += d0.h[1] * yvv;
        acc2 += d1.h[0] * yvv;
        acc3 += d1.h[1] * yvv;
      }
    }

    // epilogue (R14-verified D-layout: row=x=kb*4+r, col=point=s)
    const uint* xyr = (const uint*)xy_s[pt];
    uint q0 = xyr[kb * 2], q1 = xyr[kb * 2 + 1];
    uint q2 = xyr[8 + kb * 2], q3 = xyr[8 + kb * 2 + 1];
    float v = acc0[0] * bf_lo(q0) + acc0[1] * bf_hi(q0)
            + acc1[0] * bf_lo(q1) + acc1[1] * bf_hi(q1)
            + acc2[0] * bf_lo(q2) + acc2[1] * bf_hi(q2)
            + acc3[0] * bf_lo(q3) + acc3[1] * bf_hi(q3);
    v += __shfl_xor(v, 16, 64);
    v += __shfl_xor(v, 32, 64);
    if (l < 16) part_s[wv][pt] = v;   // kb==0 lanes hold pt = t*16+s
  }
  __syncthreads();

  // cross-wave sum of y-partials (linear, exact partition of y=0..31)
  if (tid < 128)
    out[blockIdx.x * 128 + tid] =
        part_s[0][tid] + part_s[1][tid] + part_s[2][tid] + part_s[3][tid];
}

// ---------- fallback (no workspace): slow-but-correct ----------
__global__ __launch_bounds__(256) void tucker_small_k(
    const float* __restrict__ coords,
    const float* __restrict__ pxy, const float* __restrict__ pyz,
    const float* __restrict__ pxz, const float* __restrict__ g,
    float* __restrict__ out) {
  __shared__ float s_yz[256 * 33];
  int tid = threadIdx.x;
  int p = blockIdx.x * 256 + tid;
  float c0 = coords[3 * p + 0] / 1.3f;
  float c1 = coords[3 * p + 1] / 1.3f;
  float c2 = coords[3 * p + 2] / 1.3f;
  float xy[32], xz[32];
  float* yzrow = &s_yz[tid * 33];
  sample_plane_f32(pxy, c0, c1, [&](int c, float v) { xy[c] = v; });
  sample_plane_f32(pyz, c1, c2, [&](int c, float v) { yzrow[c] = v; });
  sample_plane_f32(pxz, c0, c2, [&](int c, float v) { xz[c] = v; });
  float acc = 0.0f;
  for (int y = 0; y < 32; ++y) {
    float yzv = yzrow[y];
    float accy = 0.0f;
#pragma unroll
    for (int z = 0; z < 32; ++z) {
      float t0 = 0.f, t1 = 0.f, t2 = 0.f, t3 = 0.f;
#pragma unroll
      for (int x = 0; x < 32; x += 4) {
        t0 = fmaf(g[(x + 0) * 1024 + y * 32 + z], xy[x + 0], t0);
        t1 = fmaf(g[(x + 1) * 1024 + y * 32 + z], xy[x + 1], t1);
        t2 = fmaf(g[(x + 2) * 1024 + y * 32 + z], xy[x + 2], t2);
        t3 = fmaf(g[(x + 3) * 1024 + y * 32 + z], xy[x + 3], t3);
      }
      accy = fmaf((t0 + t1) + (t2 + t3), xz[z], accy);
    }
    acc = fmaf(accy, yzv, acc);
  }
  out[p] = acc;
}

extern "C" void kernel_launch(void* const* d_in, const int* in_sizes, int n_in,
                              void* d_out, int out_size, void* d_ws, size_t ws_size,
                              hipStream_t stream) {
  const float* coords = (const float*)d_in[0];
  const float* pxy = (const float*)d_in[1];
  const float* pyz = (const float*)d_in[2];
  const float* pxz = (const float*)d_in[3];
  const float* g   = (const float*)d_in[4];
  float* out = (float*)d_out;

  if (ws_size >= WS_NEEDED) {
    ushort* planes_t = (ushort*)d_ws;
    ushort* grb = (ushort*)((char*)d_ws + WS_GRB_OFF);
    hipLaunchKernelGGL(transpose_planes_k, dim3(768), dim3(256), 0, stream,
                       pxy, pyz, pxz, planes_t);
    hipLaunchKernelGGL(prep_grb_k, dim3(128), dim3(256), 0, stream, g, grb);
    hipLaunchKernelGGL(tucker_mfma_k, dim3(NPTS / 128), dim3(256), 0, stream,
                       coords, planes_t, grb, out);
  } else {
    hipLaunchKernelGGL(tucker_small_k, dim3(NPTS / 256), dim3(256), 0, stream,
                       coords, pxy, pyz, pxz, g, out);
  }
}